// Round 3
// baseline (303.407 us; speedup 1.0000x reference)
//
#include <hip/hip_runtime.h>

// BoxFilter: 21x21 all-ones box, circular pad, x: f32[8,1,2048,2048].
// v3: one column per thread, full-window register preload (84 loads in
// flight, forced by asm fence), interior fast path without wrap arithmetic.
// Phase 2: lane=row (conflict-free LDS), wave=32-col chunk, float4 stores.

#define HH 2048
#define WW 2048
#define RAD 10
#define DIAM 21
#define TH 64
#define TW 128
#define NCOL (TW + 2 * RAD)     // 148 columns staged
#define CS_STRIDE (NCOL + 1)    // 149 (odd -> <=2-way LDS aliasing, free)
#define NROWS (TH + 2 * RAD)    // 84 rows per column window

__global__ __launch_bounds__(256, 4) void box_filter_v3(
    const float* __restrict__ x, float* __restrict__ out) {
  __shared__ float sCS[TH * CS_STRIDE];  // 38,144 B -> 4 blocks/CU

  const int n = blockIdx.z;
  const int h0 = blockIdx.y * TH;
  const int w0 = blockIdx.x * TW;
  const float* __restrict__ xp = x + (size_t)n * HH * WW;
  float* __restrict__ op = out + (size_t)n * HH * WW;
  const int tid = threadIdx.x;

  // ---- Phase 1: vertical sliding sum, one column per thread (tid < 148) ----
  if (tid < NCOL) {
    const int gc = (w0 - RAD + tid) & (WW - 1);  // circular in W
    float v[NROWS];
    if (h0 >= RAD && h0 + TH - 1 + RAD < HH) {
      // interior: rows h0-10 .. h0+73 all in range, no wrap
      const float* p = xp + (size_t)(h0 - RAD) * WW + gc;
#pragma unroll
      for (int k = 0; k < NROWS; ++k) v[k] = p[(size_t)k * WW];
    } else {
#pragma unroll
      for (int k = 0; k < NROWS; ++k)
        v[k] = xp[(size_t)((h0 - RAD + k) & (HH - 1)) * WW + gc];
    }
    // Scheduling fence: forbid sinking loads past this point -> all 84 loads
    // issued back-to-back (max MLP), single waitcnt, ~100 VGPRs live.
    asm volatile("" ::: "memory");
    float s = 0.f;
#pragma unroll
    for (int k = 0; k < DIAM; ++k) s += v[k];
    sCS[tid] = s;
#pragma unroll
    for (int i = 1; i < TH; ++i) {
      s += v[i + DIAM - 1] - v[i - 1];
      sCS[i * CS_STRIDE + tid] = s;
    }
  }
  __syncthreads();

  // ---- Phase 2: horizontal sliding sum. lane=row r (2-way LDS, free),
  // wave=cg (32-col chunk). 8 float4 stores per thread. ----
  {
    const int r = tid & 63;
    const int cg = tid >> 6;
    const float* csrow = &sCS[r * CS_STRIDE + cg * 32];
    float w_[32 + 2 * RAD];  // 52
#pragma unroll
    for (int k = 0; k < 52; ++k) w_[k] = csrow[k];
    float s = 0.f;
#pragma unroll
    for (int k = 0; k < DIAM; ++k) s += w_[k];
    float o[32];
    o[0] = s;
#pragma unroll
    for (int j = 1; j < 32; ++j) {
      s += w_[j + DIAM - 1] - w_[j - 1];
      o[j] = s;
    }
    float4* dst = (float4*)&op[(size_t)(h0 + r) * WW + w0 + cg * 32];
#pragma unroll
    for (int q = 0; q < 8; ++q)
      dst[q] = make_float4(o[4 * q], o[4 * q + 1], o[4 * q + 2], o[4 * q + 3]);
  }
}

extern "C" void kernel_launch(void* const* d_in, const int* in_sizes, int n_in,
                              void* d_out, int out_size, void* d_ws, size_t ws_size,
                              hipStream_t stream) {
  const float* x = (const float*)d_in[0];
  float* out = (float*)d_out;
  dim3 grid(WW / TW, HH / TH, 8);  // (16, 32, 8) = 4096 blocks
  dim3 block(256);
  hipLaunchKernelGGL(box_filter_v3, grid, block, 0, stream, x, out);
}